// Round 8
// baseline (59.181 us; speedup 1.0000x reference)
//
#include <hip/hip_runtime.h>
#include <hip/hip_bf16.h>
#include <stdint.h>

#define BATCH   512
#define INCH    20
#define FEAT    128
#define KACT    16
#define NUNIT   12

typedef short bf16x8 __attribute__((ext_vector_type(8)));
typedef float f32x4  __attribute__((ext_vector_type(4)));

#define BPACK_ELEMS (3*2*4*128*8)   // [ky][kk][g][f][j], k = kk*32+g*8+j -> (kx=k/20, c=k%20), 0 for k>=60
#define WHEAD_ELEMS (4*4*4*16*8)    // [agent][kt][g][action][j], f = kt*32+g*8+j

#define XIN_ELEMS   (34*34*20 + 64) // padded input [yy][xx][c] bf16 + slack for k>=60 overreads (stays zero)

__device__ __forceinline__ uint16_t f2bf(float f) {
    union { float f; uint32_t u; } x{f};
    uint32_t u = x.u;
    return (uint16_t)((u + 0x7FFFu + ((u >> 16) & 1u)) >> 16);  // RNE
}

__device__ __forceinline__ uint32_t cvt_pk_bf16(float lo, float hi) {
    uint32_t r;
    asm("v_cvt_pk_bf16_f32 %0, %1, %2" : "=v"(r) : "v"(lo), "v"(hi));
    return r;
}

// ---- One-time weight repack (fp32 -> bf16 fragment order) ----
__global__ void repack_kernel(const float* __restrict__ conv_w,
                              const float* __restrict__ W_all,
                              uint16_t* __restrict__ Bpack,
                              uint16_t* __restrict__ Whead) {
    int idx = blockIdx.x * 256 + threadIdx.x;
    if (idx < BPACK_ELEMS) {
        int j = idx & 7, t = idx >> 3;
        int f = t & 127; t >>= 7;
        int g = t & 3;   t >>= 2;
        int kk = t & 1;  int ky = t >> 1;
        int k = kk * 32 + g * 8 + j;
        float v = 0.0f;
        if (k < 60) {
            int kx = k / 20, c = k % 20;
            v = conv_w[((f * INCH + c) * 3 + ky) * 3 + kx];
        }
        Bpack[idx] = f2bf(v);
    } else if (idx < BPACK_ELEMS + WHEAD_ELEMS) {
        int i = idx - BPACK_ELEMS;
        int j = i & 7, t = i >> 3;
        int a = t & 15; t >>= 4;
        int g = t & 3;  t >>= 2;
        int kt = t & 3; int ag = t >> 2;
        int f = kt * 32 + g * 8 + j;
        Whead[i] = f2bf(W_all[(ag * KACT + a) * FEAT + f]);
    }
}

// ---- Fused conv3x3 + relu/bias/mask + per-sample head GEMM ----
// Feature-split: 8 waves = 2 row-waves x 4 feature-quarters, 4 waves/SIMD.
// Software-rotated pipeline: head(s-1) is interleaved with conv(s) (legal via
// the xl double buffer), so post-barrier LDS latency hides under conv work.
__global__ __launch_bounds__(512, 4) void fused_mfma_kernel(
    const float* __restrict__ states,    // [512,20,32,32]
    const int*   __restrict__ labels,    // [512]
    const float* __restrict__ maskings,  // [512,1,32,32]
    const float* __restrict__ conv_b,    // [128]
    const float* __restrict__ b_all,     // [4,16]
    const uint16_t* __restrict__ Bpack,
    const uint16_t* __restrict__ Whead,
    float*       __restrict__ out)       // [512*1024*12] ++ [512*1024*4]
{
    __shared__ __align__(16) uint16_t xin[XIN_ELEMS];   // 46,368 B
    __shared__ __align__(16) uint16_t xl[2 * 64 * 128]; // 32,768 B, [buf][pos][feat] swizzled

    const int b    = blockIdx.x;
    const int tid  = threadIdx.x;
    const int lane = tid & 63;
    const int w    = tid >> 6;     // 0..7
    const int l15  = lane & 15;
    const int g    = lane >> 4;    // 0..3
    const int wr   = w >> 2;       // 0..1 : row within step
    const int fq   = w & 3;        // 0..3 : feature quarter (feats fq*32..+31)
    const int swz  = (l15 & 7) << 4;   // XOR swizzle for xl (pos = l15 on both sides)

    // ---- zero xin (incl. border + slack) ----
    for (int i = tid; i < XIN_ELEMS / 8; i += 512)
        ((uint4*)xin)[i] = uint4{0, 0, 0, 0};
    __syncthreads();

    // ---- stage input: [c][y][x] fp32 -> xin[pos][c] bf16, b64 writes ----
    for (int t = 0; t < 10; ++t) {
        int i  = t * 512 + tid;
        int p  = i & 1023;
        int cg = i >> 10;           // 0..4 (channels cg*4 .. +3)
        int y  = p >> 5, x = p & 31;
        const float* sp = states + (size_t)b * (INCH * 1024) + cg * 4096 + p;
        float v0 = sp[0], v1 = sp[1024], v2 = sp[2048], v3 = sp[3072];
        uint64_t lo = cvt_pk_bf16(v0, v1);
        uint64_t hi = cvt_pk_bf16(v2, v3);
        *(uint64_t*)&xin[((y + 1) * 34 + (x + 1)) * 20 + cg * 4] = lo | (hi << 32);
    }

    // ---- per-lane invariants ----
    const int label = labels[b];
    f32x4 cb[2];                       // conv bias: f = fq*32 + nt*16 + g*4 + j
    #pragma unroll
    for (int nt = 0; nt < 2; ++nt)
        cb[nt] = *(const f32x4*)&conv_b[fq * 32 + nt * 16 + g * 4];
    const f32x4 hb = *(const f32x4*)&b_all[label * KACT + g * 4];  // actions g*4..+3
    bf16x8 Wh[4];                      // head A-frags: lane l15 = action, k = g*8+j
    #pragma unroll
    for (int kt = 0; kt < 4; ++kt)
        Wh[kt] = *(const bf16x8*)&Whead[(((label * 4 + kt) * 4 + g) * 16 + l15) * 8];

    // conv A-frags for this wave's feature quarter: 12 frags = 48 VGPRs
    bf16x8 Wc[3][2][2];
    #pragma unroll
    for (int ky = 0; ky < 3; ++ky)
        #pragma unroll
        for (int kk = 0; kk < 2; ++kk)
            #pragma unroll
            for (int nt = 0; nt < 2; ++nt)
                Wc[ky][kk][nt] = *(const bf16x8*)
                    &Bpack[((((ky * 2 + kk) * 4 + g) * 128 + fq * 32 + nt * 16 + l15) * 8)];

    const int hoff0 = ((wr * 2 + fq) * 16 + l15) * 256;  // head read byte base (pos row)
    const bool do_head = (fq < 2);

    __syncthreads();  // xin fully staged

    // ---- 16 steps; step s: conv rows y = s*2 + wr, head for step s-1 ----
    #pragma unroll 2
    for (int s = 0; s < 16; ++s) {
        const int y = s * 2 + wr;

        // masks for this step's epilogue (issue early)
        const float m0 = maskings[(size_t)b * 1024 + y * 32 + l15];
        const float m1 = maskings[(size_t)b * 1024 + y * 32 + 16 + l15];

        // (a) head(s-1) xl reads -- first LDS issue after the barrier
        bf16x8 hx[4];
        char* hrd = (char*)xl + ((s + 1) & 1) * 16384;   // (s-1)&1 == (s+1)&1
        if (do_head && s > 0) {
            #pragma unroll
            for (int kt = 0; kt < 4; ++kt)
                hx[kt] = *(const bf16x8*)(hrd + ((hoff0 + kt * 64 + g * 16) ^ swz));
        }

        // (b) conv MFMAs for step s
        f32x4 acc[2][2];   // [ptile][nt]
        #pragma unroll
        for (int pt = 0; pt < 2; ++pt)
            #pragma unroll
            for (int nt = 0; nt < 2; ++nt)
                acc[pt][nt] = f32x4{0.f, 0.f, 0.f, 0.f};

        __builtin_amdgcn_s_setprio(1);
        #pragma unroll
        for (int ky = 0; ky < 3; ++ky) {
            const uint64_t* a0 = (const uint64_t*)&xin[((y + ky) * 34 + l15) * 20 + g * 8];
            const uint64_t* a1 = (const uint64_t*)&xin[((y + ky) * 34 + 16 + l15) * 20 + g * 8];
            #pragma unroll
            for (int kk = 0; kk < 2; ++kk) {
                union { uint64_t u[2]; bf16x8 v; } B0, B1;
                B0.u[0] = a0[kk * 8 + 0]; B0.u[1] = a0[kk * 8 + 1];
                B1.u[0] = a1[kk * 8 + 0]; B1.u[1] = a1[kk * 8 + 1];
                #pragma unroll
                for (int nt = 0; nt < 2; ++nt) {
                    acc[0][nt] = __builtin_amdgcn_mfma_f32_16x16x32_bf16(
                        Wc[ky][kk][nt], B0.v, acc[0][nt], 0, 0, 0);
                    acc[1][nt] = __builtin_amdgcn_mfma_f32_16x16x32_bf16(
                        Wc[ky][kk][nt], B1.v, acc[1][nt], 0, 0, 0);
                }
            }
        }
        __builtin_amdgcn_s_setprio(0);

        // (c) head(s-1) MFMAs + coalesced store (hx long ready by now)
        if (do_head && s > 0) {
            f32x4 hacc = f32x4{0.f, 0.f, 0.f, 0.f};
            __builtin_amdgcn_s_setprio(1);
            #pragma unroll
            for (int kt = 0; kt < 4; ++kt)
                hacc = __builtin_amdgcn_mfma_f32_16x16x32_bf16(Wh[kt], hx[kt], hacc, 0, 0, 0);
            __builtin_amdgcn_s_setprio(0);
            const size_t pos = (size_t)b * 1024 + ((s - 1) * 2 + wr) * 32 + fq * 16 + l15;
            f32x4 o = hacc + hb;
            if (g < 3) *(f32x4*)&out[pos * NUNIT + g * 4] = o;
            else       *(f32x4*)&out[(size_t)BATCH * 1024 * NUNIT + pos * 4] = o;
        }

        // (d) epilogue: bias+relu+mask, pack bf16, swizzled write into xl[s&1]
        char* xbase = (char*)xl + (s & 1) * 16384;
        #pragma unroll
        for (int pt = 0; pt < 2; ++pt) {
            const float m = pt ? m1 : m0;
            #pragma unroll
            for (int nt = 0; nt < 2; ++nt) {
                float x0 = fmaxf(acc[pt][nt][0] + cb[nt][0], 0.f) * m;
                float x1 = fmaxf(acc[pt][nt][1] + cb[nt][1], 0.f) * m;
                float x2 = fmaxf(acc[pt][nt][2] + cb[nt][2], 0.f) * m;
                float x3 = fmaxf(acc[pt][nt][3] + cb[nt][3], 0.f) * m;
                uint64_t pk = (uint64_t)cvt_pk_bf16(x0, x1)
                            | ((uint64_t)cvt_pk_bf16(x2, x3) << 32);
                const int off = ((wr * 2 + pt) * 16 + l15) * 256 + fq * 64 + nt * 32 + g * 8;
                *(uint64_t*)(xbase + (off ^ swz)) = pk;
            }
        }

        __syncthreads();  // xl[s&1] complete
    }

    // ---- tail: head(15) from xl buf 1 ----
    if (do_head) {
        char* hrd = (char*)xl + 16384;
        f32x4 hacc = f32x4{0.f, 0.f, 0.f, 0.f};
        #pragma unroll
        for (int kt = 0; kt < 4; ++kt) {
            bf16x8 hx = *(const bf16x8*)(hrd + ((hoff0 + kt * 64 + g * 16) ^ swz));
            hacc = __builtin_amdgcn_mfma_f32_16x16x32_bf16(Wh[kt], hx, hacc, 0, 0, 0);
        }
        const size_t pos = (size_t)b * 1024 + (30 + wr) * 32 + fq * 16 + l15;
        f32x4 o = hacc + hb;
        if (g < 3) *(f32x4*)&out[pos * NUNIT + g * 4] = o;
        else       *(f32x4*)&out[(size_t)BATCH * 1024 * NUNIT + pos * 4] = o;
    }
}

extern "C" void kernel_launch(void* const* d_in, const int* in_sizes, int n_in,
                              void* d_out, int out_size, void* d_ws, size_t ws_size,
                              hipStream_t stream) {
    const float* states   = (const float*)d_in[0];
    const int*   labels   = (const int*)d_in[1];
    const float* maskings = (const float*)d_in[2];
    const float* conv_w   = (const float*)d_in[3];
    const float* conv_b   = (const float*)d_in[4];
    const float* W_all    = (const float*)d_in[5];
    const float* b_all    = (const float*)d_in[6];
    float* out = (float*)d_out;

    uint16_t* Bpack = (uint16_t*)d_ws;
    uint16_t* Whead = Bpack + BPACK_ELEMS;

    repack_kernel<<<(BPACK_ELEMS + WHEAD_ELEMS + 255) / 256, 256, 0, stream>>>(
        conv_w, W_all, Bpack, Whead);
    fused_mfma_kernel<<<BATCH, 512, 0, stream>>>(
        states, labels, maskings, conv_b, b_all, Bpack, Whead, out);
}

// Round 9
// 41.303 us; speedup vs baseline: 1.4329x; 1.4329x over previous
//
#include <hip/hip_runtime.h>
#include <hip/hip_bf16.h>
#include <stdint.h>

#define BATCH   512
#define INCH    20
#define FEAT    128
#define KACT    16
#define NUNIT   12

typedef short bf16x8 __attribute__((ext_vector_type(8)));
typedef float f32x4  __attribute__((ext_vector_type(4)));

#define BPACK_ELEMS (3*2*4*128*8)   // [ky][kk][g][f][j], k = kk*32+g*8+j -> (kx=k/20, c=k%20), 0 for k>=60
#define WHEAD_ELEMS (4*4*4*16*8)    // [agent][kt][g][action][j], f = kt*32+g*8+j

#define XIN_ELEMS   (34*34*20 + 64) // padded input [yy][xx][c] bf16 + slack for k>=60 overreads (stays zero)

__device__ __forceinline__ uint16_t f2bf(float f) {
    union { float f; uint32_t u; } x{f};
    uint32_t u = x.u;
    return (uint16_t)((u + 0x7FFFu + ((u >> 16) & 1u)) >> 16);  // RNE
}

__device__ __forceinline__ uint32_t cvt_pk_bf16(float lo, float hi) {
    uint32_t r;
    asm("v_cvt_pk_bf16_f32 %0, %1, %2" : "=v"(r) : "v"(lo), "v"(hi));
    return r;
}

// Workgroup barrier WITHOUT the vmcnt(0) drain: only LDS ordering is needed
// across the per-step barrier (epi ds_write -> head ds_read). Global out-stores
// stay in flight (<=16 outstanding, cap is 63). T4: never drain vmcnt in-loop.
__device__ __forceinline__ void lds_barrier() {
    asm volatile("s_waitcnt lgkmcnt(0)\n\ts_barrier" ::: "memory");
}

// ---- One-time weight repack (fp32 -> bf16 fragment order) ----
__global__ void repack_kernel(const float* __restrict__ conv_w,
                              const float* __restrict__ W_all,
                              uint16_t* __restrict__ Bpack,
                              uint16_t* __restrict__ Whead) {
    int idx = blockIdx.x * 256 + threadIdx.x;
    if (idx < BPACK_ELEMS) {
        int j = idx & 7, t = idx >> 3;
        int f = t & 127; t >>= 7;
        int g = t & 3;   t >>= 2;
        int kk = t & 1;  int ky = t >> 1;
        int k = kk * 32 + g * 8 + j;
        float v = 0.0f;
        if (k < 60) {
            int kx = k / 20, c = k % 20;
            v = conv_w[((f * INCH + c) * 3 + ky) * 3 + kx];
        }
        Bpack[idx] = f2bf(v);
    } else if (idx < BPACK_ELEMS + WHEAD_ELEMS) {
        int i = idx - BPACK_ELEMS;
        int j = i & 7, t = i >> 3;
        int a = t & 15; t >>= 4;
        int g = t & 3;  t >>= 2;
        int kt = t & 3; int ag = t >> 2;
        int f = kt * 32 + g * 8 + j;
        Whead[i] = f2bf(W_all[(ag * KACT + a) * FEAT + f]);
    }
}

// ---- Fused conv3x3 + relu/bias/mask + per-sample head GEMM ----
// Feature-split: 8 waves = 2 row-waves x 4 feature-quarters, 4 waves/SIMD.
// One lgkm-only barrier per step; head runs post-barrier (R7 structure).
__global__ __launch_bounds__(512, 4) void fused_mfma_kernel(
    const float* __restrict__ states,    // [512,20,32,32]
    const int*   __restrict__ labels,    // [512]
    const float* __restrict__ maskings,  // [512,1,32,32]
    const float* __restrict__ conv_b,    // [128]
    const float* __restrict__ b_all,     // [4,16]
    const uint16_t* __restrict__ Bpack,
    const uint16_t* __restrict__ Whead,
    float*       __restrict__ out)       // [512*1024*12] ++ [512*1024*4]
{
    __shared__ __align__(16) uint16_t xin[XIN_ELEMS];   // 46,368 B
    __shared__ __align__(16) uint16_t xl[2 * 64 * 128]; // 32,768 B, [buf][pos][feat] swizzled

    const int b    = blockIdx.x;
    const int tid  = threadIdx.x;
    const int lane = tid & 63;
    const int w    = tid >> 6;     // 0..7
    const int l15  = lane & 15;
    const int g    = lane >> 4;    // 0..3
    const int wr   = w >> 2;       // 0..1 : row within step
    const int fq   = w & 3;        // 0..3 : feature quarter (feats fq*32..+31)
    const int swz  = (l15 & 7) << 4;   // XOR swizzle for xl (pos = l15 on both sides)

    // ---- zero xin (incl. border + slack) ----
    for (int i = tid; i < XIN_ELEMS / 8; i += 512)
        ((uint4*)xin)[i] = uint4{0, 0, 0, 0};
    __syncthreads();

    // ---- stage input: [c][y][x] fp32 -> xin[pos][c] bf16, b64 writes ----
    for (int t = 0; t < 10; ++t) {
        int i  = t * 512 + tid;
        int p  = i & 1023;
        int cg = i >> 10;           // 0..4 (channels cg*4 .. +3)
        int y  = p >> 5, x = p & 31;
        const float* sp = states + (size_t)b * (INCH * 1024) + cg * 4096 + p;
        float v0 = sp[0], v1 = sp[1024], v2 = sp[2048], v3 = sp[3072];
        uint64_t lo = cvt_pk_bf16(v0, v1);
        uint64_t hi = cvt_pk_bf16(v2, v3);
        *(uint64_t*)&xin[((y + 1) * 34 + (x + 1)) * 20 + cg * 4] = lo | (hi << 32);
    }

    // ---- per-lane invariants ----
    const int label = labels[b];
    f32x4 cb[2];                       // conv bias: f = fq*32 + nt*16 + g*4 + j
    #pragma unroll
    for (int nt = 0; nt < 2; ++nt)
        cb[nt] = *(const f32x4*)&conv_b[fq * 32 + nt * 16 + g * 4];
    const f32x4 hb = *(const f32x4*)&b_all[label * KACT + g * 4];  // actions g*4..+3
    bf16x8 Wh[4];                      // head A-frags: lane l15 = action, k = g*8+j
    #pragma unroll
    for (int kt = 0; kt < 4; ++kt)
        Wh[kt] = *(const bf16x8*)&Whead[(((label * 4 + kt) * 4 + g) * 16 + l15) * 8];

    // conv A-frags for this wave's feature quarter: 12 frags = 48 VGPRs
    bf16x8 Wc[3][2][2];
    #pragma unroll
    for (int ky = 0; ky < 3; ++ky)
        #pragma unroll
        for (int kk = 0; kk < 2; ++kk)
            #pragma unroll
            for (int nt = 0; nt < 2; ++nt)
                Wc[ky][kk][nt] = *(const bf16x8*)
                    &Bpack[((((ky * 2 + kk) * 4 + g) * 128 + fq * 32 + nt * 16 + l15) * 8)];

    const int hoff0 = ((wr * 2 + fq) * 16 + l15) * 256;  // head read byte base (pos row)
    const bool do_head = (fq < 2);

    __syncthreads();  // xin fully staged (full drain OK here, once)

    // ---- 16 steps; step s: rows y = s*2 + wr; one lgkm-only barrier per step ----
    #pragma unroll 2
    for (int s = 0; s < 16; ++s) {
        const int y = s * 2 + wr;

        // prefetch masks (issue early; consumed in epilogue)
        const float m0 = maskings[(size_t)b * 1024 + y * 32 + l15];
        const float m1 = maskings[(size_t)b * 1024 + y * 32 + 16 + l15];

        f32x4 acc[2][2];   // [ptile][nt] : D[f = fq*32+nt*16+g*4+j][p = pt*16+l15]
        #pragma unroll
        for (int pt = 0; pt < 2; ++pt)
            #pragma unroll
            for (int nt = 0; nt < 2; ++nt)
                acc[pt][nt] = f32x4{0.f, 0.f, 0.f, 0.f};

        // conv: A = resident quarter-weights, B = im2col rows from xin
        __builtin_amdgcn_s_setprio(1);
        #pragma unroll
        for (int ky = 0; ky < 3; ++ky) {
            const uint64_t* a0 = (const uint64_t*)&xin[((y + ky) * 34 + l15) * 20 + g * 8];
            const uint64_t* a1 = (const uint64_t*)&xin[((y + ky) * 34 + 16 + l15) * 20 + g * 8];
            #pragma unroll
            for (int kk = 0; kk < 2; ++kk) {
                union { uint64_t u[2]; bf16x8 v; } B0, B1;
                B0.u[0] = a0[kk * 8 + 0]; B0.u[1] = a0[kk * 8 + 1];
                B1.u[0] = a1[kk * 8 + 0]; B1.u[1] = a1[kk * 8 + 1];
                #pragma unroll
                for (int nt = 0; nt < 2; ++nt) {
                    acc[0][nt] = __builtin_amdgcn_mfma_f32_16x16x32_bf16(
                        Wc[ky][kk][nt], B0.v, acc[0][nt], 0, 0, 0);
                    acc[1][nt] = __builtin_amdgcn_mfma_f32_16x16x32_bf16(
                        Wc[ky][kk][nt], B1.v, acc[1][nt], 0, 0, 0);
                }
            }
        }
        __builtin_amdgcn_s_setprio(0);

        // epilogue: bias+relu+mask, pack bf16, swizzled write into xl[s&1]
        char* xbase = (char*)xl + (s & 1) * 16384;
        #pragma unroll
        for (int pt = 0; pt < 2; ++pt) {
            const float m = pt ? m1 : m0;
            #pragma unroll
            for (int nt = 0; nt < 2; ++nt) {
                float x0 = fmaxf(acc[pt][nt][0] + cb[nt][0], 0.f) * m;
                float x1 = fmaxf(acc[pt][nt][1] + cb[nt][1], 0.f) * m;
                float x2 = fmaxf(acc[pt][nt][2] + cb[nt][2], 0.f) * m;
                float x3 = fmaxf(acc[pt][nt][3] + cb[nt][3], 0.f) * m;
                uint64_t pk = (uint64_t)cvt_pk_bf16(x0, x1)
                            | ((uint64_t)cvt_pk_bf16(x2, x3) << 32);
                const int off = ((wr * 2 + pt) * 16 + l15) * 256 + fq * 64 + nt * 32 + g * 8;
                *(uint64_t*)(xbase + (off ^ swz)) = pk;
            }
        }

        lds_barrier();  // xl[s&1] complete; out-stores stay in flight (no vmcnt drain)

        // head: waves fq<2 do ptile (wr, pt=fq); K=128 = 4 kt slices
        if (do_head) {
            f32x4 hacc = f32x4{0.f, 0.f, 0.f, 0.f};
            __builtin_amdgcn_s_setprio(1);
            #pragma unroll
            for (int kt = 0; kt < 4; ++kt) {
                const int off = hoff0 + kt * 64 + g * 16;
                bf16x8 bx = *(const bf16x8*)(xbase + (off ^ swz));
                hacc = __builtin_amdgcn_mfma_f32_16x16x32_bf16(Wh[kt], bx, hacc, 0, 0, 0);
            }
            __builtin_amdgcn_s_setprio(0);
            const size_t pos = (size_t)b * 1024 + y * 32 + fq * 16 + l15;
            f32x4 o = hacc + hb;
            if (g < 3) *(f32x4*)&out[pos * NUNIT + g * 4] = o;                    // actions 0..11
            else       *(f32x4*)&out[(size_t)BATCH * 1024 * NUNIT + pos * 4] = o; // actions 12..15
        }
    }
}

extern "C" void kernel_launch(void* const* d_in, const int* in_sizes, int n_in,
                              void* d_out, int out_size, void* d_ws, size_t ws_size,
                              hipStream_t stream) {
    const float* states   = (const float*)d_in[0];
    const int*   labels   = (const int*)d_in[1];
    const float* maskings = (const float*)d_in[2];
    const float* conv_w   = (const float*)d_in[3];
    const float* conv_b   = (const float*)d_in[4];
    const float* W_all    = (const float*)d_in[5];
    const float* b_all    = (const float*)d_in[6];
    float* out = (float*)d_out;

    uint16_t* Bpack = (uint16_t*)d_ws;
    uint16_t* Whead = Bpack + BPACK_ELEMS;

    repack_kernel<<<(BPACK_ELEMS + WHEAD_ELEMS + 255) / 256, 256, 0, stream>>>(
        conv_w, W_all, Bpack, Whead);
    fused_mfma_kernel<<<BATCH, 512, 0, stream>>>(
        states, labels, maskings, conv_b, b_all, Bpack, Whead, out);
}